// Round 1
// baseline (503.087 us; speedup 1.0000x reference)
//
#include <hip/hip_runtime.h>
#include <float.h>

#define NP 8192
#define WPB 8            // waves per block
#define BLK (WPB * 64)   // 512 threads
#define CHUNK 4096       // candidates staged per LDS chunk (48 KB SoA)

// ws layout (floats):
//  0*NP  pc1 x | 1*NP pc1 y | 2*NP pc1 z
//  3*NP  pc2 x,y,z
//  6*NP  warp x,y,z
//  9*NP  flow x,y,z
// 12*NP  c2curv x,y,z
// 15*NP  mcurv x,y,z
// 18*NP  acc[0]=chamfer acc[1]=smooth acc[2]=curv

__device__ __forceinline__ float wavemin_f(float v) {
#pragma unroll
  for (int s = 1; s < 64; s <<= 1) v = fminf(v, __shfl_xor(v, s, 64));
  return v;
}

__device__ __forceinline__ unsigned long long wavemin_u64(unsigned long long k) {
#pragma unroll
  for (int s = 1; s < 64; s <<= 1) {
    unsigned long long o = __shfl_xor(k, s, 64);
    k = (o < k) ? o : k;
  }
  return k;
}

// 512 threads copy CHUNK floats per array (2 x float4 each)
__device__ __forceinline__ void stage_chunk(const float* __restrict__ gx,
                                            const float* __restrict__ gy,
                                            const float* __restrict__ gz,
                                            float* sx, float* sy, float* sz) {
  const int idx = threadIdx.x * 4;
  *(float4*)(sx + idx)        = *(const float4*)(gx + idx);
  *(float4*)(sy + idx)        = *(const float4*)(gy + idx);
  *(float4*)(sz + idx)        = *(const float4*)(gz + idx);
  *(float4*)(sx + idx + 2048) = *(const float4*)(gx + idx + 2048);
  *(float4*)(sy + idx + 2048) = *(const float4*)(gy + idx + 2048);
  *(float4*)(sz + idx + 2048) = *(const float4*)(gz + idx + 2048);
}

// per-lane sorted top-K with wave-shared threshold gate.
// Gate is lossless: thr = min over lanes of that lane's kept K-th smallest,
// which upper-bounds the final global K-th smallest.
template<int K>
__device__ __forceinline__ void scan_chunk(const float* __restrict__ sx,
                                           const float* __restrict__ sy,
                                           const float* __restrict__ sz,
                                           int jbase, float qx, float qy, float qz,
                                           float (&ds)[K], int (&js)[K], float& thr) {
  const int lane = threadIdx.x & 63;
  for (int jl = lane; jl < CHUNK; jl += 64) {
    float dx = sx[jl] - qx;
    float dy = sy[jl] - qy;
    float dz = sz[jl] - qz;
    float d = dx * dx + dy * dy + dz * dz;
    if (__ballot(d < thr) != 0ULL) {
      if (d < ds[K - 1]) {
        ds[K - 1] = d; js[K - 1] = jbase + jl;
#pragma unroll
        for (int t = K - 1; t > 0; --t) {
          float a = ds[t - 1], b = ds[t];
          int ia = js[t - 1], ib = js[t];
          bool sw = b < a;
          ds[t - 1] = sw ? b : a;  ds[t] = sw ? a : b;
          js[t - 1] = sw ? ib : ia; js[t] = sw ? ia : ib;
        }
      }
      thr = wavemin_f(ds[K - 1]);
    }
  }
}

template<int K>
__device__ __forceinline__ void init_topk(float (&ds)[K], int (&js)[K]) {
#pragma unroll
  for (int t = 0; t < K; ++t) { ds[t] = FLT_MAX; js[t] = 0; }
}

// merge round r: returns wave-uniform winner key; caller extracts (d, j).
template<int K>
__device__ __forceinline__ unsigned long long merge_round(float (&ds)[K], int (&js)[K]) {
  unsigned long long key =
      ((unsigned long long)__float_as_uint(ds[0]) << 32) | (unsigned)js[0];
  unsigned long long w = wavemin_u64(key);
  if (w == key) {
#pragma unroll
    for (int t = 0; t < K - 1; ++t) { ds[t] = ds[t + 1]; js[t] = js[t + 1]; }
    ds[K - 1] = FLT_MAX; js[K - 1] = 0;
  }
  return w;
}

__global__ void k_prep(const float* __restrict__ pred, const float* __restrict__ gt,
                       const float* __restrict__ coords, float* __restrict__ ws) {
  int i = blockIdx.x * blockDim.x + threadIdx.x;
  if (i < NP) {
    float cx = coords[3 * i], cy = coords[3 * i + 1], cz = coords[3 * i + 2];
    float gx = gt[3 * i],     gy = gt[3 * i + 1],     gz = gt[3 * i + 2];
    float px = pred[3 * i],   py = pred[3 * i + 1],   pz = pred[3 * i + 2];
    ws[0 * NP + i] = cx;      ws[1 * NP + i] = cy;      ws[2 * NP + i] = cz;
    ws[3 * NP + i] = cx + gx; ws[4 * NP + i] = cy + gy; ws[5 * NP + i] = cz + gz;
    ws[6 * NP + i] = cx + px; ws[7 * NP + i] = cy + py; ws[8 * NP + i] = cz + pz;
    ws[9 * NP + i] = px;      ws[10 * NP + i] = py;     ws[11 * NP + i] = pz;
  }
  if (i < 4) ws[18 * NP + i] = 0.f;
}

// pass 1: pc2 x pc2 top-10 -> c2curv
__global__ __launch_bounds__(BLK) void k_curv_pc2(float* __restrict__ ws) {
  __shared__ __align__(16) float sx[CHUNK], sy[CHUNK], sz[CHUNK];
  const float* px = ws + 3 * NP;
  const float* py = ws + 4 * NP;
  const float* pz = ws + 5 * NP;
  const int wave = threadIdx.x >> 6, lane = threadIdx.x & 63;
  const int i = blockIdx.x * WPB + wave;
  const float qx = px[i], qy = py[i], qz = pz[i];
  float ds[10]; int js[10]; init_topk(ds, js);
  float thr = FLT_MAX;
  for (int c = 0; c < NP; c += CHUNK) {
    __syncthreads();
    stage_chunk(px + c, py + c, pz + c, sx, sy, sz);
    __syncthreads();
    scan_chunk<10>(sx, sy, sz, c, qx, qy, qz, ds, js, thr);
  }
  float ax = 0.f, ay = 0.f, az = 0.f;
#pragma unroll
  for (int r = 0; r < 10; ++r) {
    unsigned long long w = merge_round(ds, js);
    int wj = (int)(w & 0xffffffffULL);
    ax += px[wj]; ay += py[wj]; az += pz[wj];
  }
  if (lane == 0) {
    const float inv9 = 1.f / 9.f;
    ws[12 * NP + i] = (ax - 10.f * qx) * inv9;
    ws[13 * NP + i] = (ay - 10.f * qy) * inv9;
    ws[14 * NP + i] = (az - 10.f * qz) * inv9;
  }
}

// pass 2: pc1 x pc1 top-10 -> mcurv (via warp) + smooth (top-9, flow norms)
__global__ __launch_bounds__(BLK) void k_pc1(float* __restrict__ ws) {
  __shared__ __align__(16) float sx[CHUNK], sy[CHUNK], sz[CHUNK];
  __shared__ float red[WPB];
  const float* px = ws;
  const float* py = ws + NP;
  const float* pz = ws + 2 * NP;
  const float* wx = ws + 6 * NP;
  const float* wy = ws + 7 * NP;
  const float* wz = ws + 8 * NP;
  const float* fx = ws + 9 * NP;
  const float* fy = ws + 10 * NP;
  const float* fz = ws + 11 * NP;
  const int wave = threadIdx.x >> 6, lane = threadIdx.x & 63;
  const int i = blockIdx.x * WPB + wave;
  const float qx = px[i], qy = py[i], qz = pz[i];
  float ds[10]; int js[10]; init_topk(ds, js);
  float thr = FLT_MAX;
  for (int c = 0; c < NP; c += CHUNK) {
    __syncthreads();
    stage_chunk(px + c, py + c, pz + c, sx, sy, sz);
    __syncthreads();
    scan_chunk<10>(sx, sy, sz, c, qx, qy, qz, ds, js, thr);
  }
  const float fix = fx[i], fiy = fy[i], fiz = fz[i];
  const float wix = wx[i], wiy = wy[i], wiz = wz[i];
  float ax = 0.f, ay = 0.f, az = 0.f, sm = 0.f;
#pragma unroll
  for (int r = 0; r < 10; ++r) {
    unsigned long long w = merge_round(ds, js);
    int wj = (int)(w & 0xffffffffULL);
    ax += wx[wj]; ay += wy[wj]; az += wz[wj];
    if (r < 9) {
      float gx_ = fx[wj] - fix, gy_ = fy[wj] - fiy, gz_ = fz[wj] - fiz;
      sm += sqrtf(gx_ * gx_ + gy_ * gy_ + gz_ * gz_);
    }
  }
  if (lane == 0) {
    const float inv9 = 1.f / 9.f;
    ws[15 * NP + i] = (ax - 10.f * wix) * inv9;
    ws[16 * NP + i] = (ay - 10.f * wiy) * inv9;
    ws[17 * NP + i] = (az - 10.f * wiz) * inv9;
    red[wave] = sm * 0.125f;
  }
  __syncthreads();
  if (threadIdx.x == 0) {
    float s = 0.f;
#pragma unroll
    for (int t = 0; t < WPB; ++t) s += red[t];
    atomicAdd(ws + 18 * NP + 1, s);
  }
}

// pass 3: warp x pc2 top-5 -> chamfer dist1 + interpolated-curvature loss
__global__ __launch_bounds__(BLK) void k_cross(float* __restrict__ ws) {
  __shared__ __align__(16) float sx[CHUNK], sy[CHUNK], sz[CHUNK];
  __shared__ float redc[WPB], redv[WPB];
  const float* px = ws + 3 * NP;   // pc2 candidates
  const float* py = ws + 4 * NP;
  const float* pz = ws + 5 * NP;
  const float* wx = ws + 6 * NP;   // warp queries
  const float* wy = ws + 7 * NP;
  const float* wz = ws + 8 * NP;
  const float* cx = ws + 12 * NP;  // c2curv
  const float* cy = ws + 13 * NP;
  const float* cz = ws + 14 * NP;
  const float* mx = ws + 15 * NP;  // mcurv
  const float* my = ws + 16 * NP;
  const float* mz = ws + 17 * NP;
  const int wave = threadIdx.x >> 6, lane = threadIdx.x & 63;
  const int i = blockIdx.x * WPB + wave;
  const float qx = wx[i], qy = wy[i], qz = wz[i];
  float ds[5]; int js[5]; init_topk(ds, js);
  float thr = FLT_MAX;
  for (int c = 0; c < NP; c += CHUNK) {
    __syncthreads();
    stage_chunk(px + c, py + c, pz + c, sx, sy, sz);
    __syncthreads();
    scan_chunk<5>(sx, sy, sz, c, qx, qy, qz, ds, js, thr);
  }
  float wsum = 0.f, ix = 0.f, iy = 0.f, iz = 0.f, d1 = 0.f;
#pragma unroll
  for (int r = 0; r < 5; ++r) {
    unsigned long long w = merge_round(ds, js);
    float wd = __uint_as_float((unsigned)(w >> 32));
    int wj = (int)(w & 0xffffffffULL);
    if (r == 0) d1 = wd;
    float wt = 1.f / (wd + 1e-8f);
    wsum += wt;
    ix += wt * cx[wj]; iy += wt * cy[wj]; iz += wt * cz[wj];
  }
  float inv = 1.f / wsum;
  float ex = ix * inv - mx[i];
  float ey = iy * inv - my[i];
  float ez = iz * inv - mz[i];
  float cv = ex * ex + ey * ey + ez * ez;
  if (lane == 0) { redc[wave] = d1; redv[wave] = cv; }
  __syncthreads();
  if (threadIdx.x == 0) {
    float sc = 0.f, sv = 0.f;
#pragma unroll
    for (int t = 0; t < WPB; ++t) { sc += redc[t]; sv += redv[t]; }
    atomicAdd(ws + 18 * NP + 0, sc);
    atomicAdd(ws + 18 * NP + 2, sv);
  }
}

// pass 4: pc2 x warp top-1 -> chamfer dist2
__global__ __launch_bounds__(BLK) void k_rev(float* __restrict__ ws) {
  __shared__ __align__(16) float sx[CHUNK], sy[CHUNK], sz[CHUNK];
  __shared__ float red[WPB];
  const float* px = ws + 6 * NP;   // warp candidates
  const float* py = ws + 7 * NP;
  const float* pz = ws + 8 * NP;
  const float* gx = ws + 3 * NP;   // pc2 queries
  const float* gy = ws + 4 * NP;
  const float* gz = ws + 5 * NP;
  const int wave = threadIdx.x >> 6, lane = threadIdx.x & 63;
  const int i = blockIdx.x * WPB + wave;
  const float qx = gx[i], qy = gy[i], qz = gz[i];
  float m = FLT_MAX;
  for (int c = 0; c < NP; c += CHUNK) {
    __syncthreads();
    stage_chunk(px + c, py + c, pz + c, sx, sy, sz);
    __syncthreads();
    for (int jl = lane; jl < CHUNK; jl += 64) {
      float dx = sx[jl] - qx;
      float dy = sy[jl] - qy;
      float dz = sz[jl] - qz;
      m = fminf(m, dx * dx + dy * dy + dz * dz);
    }
  }
  m = wavemin_f(m);
  if (lane == 0) red[wave] = m;
  __syncthreads();
  if (threadIdx.x == 0) {
    float s = 0.f;
#pragma unroll
    for (int t = 0; t < WPB; ++t) s += red[t];
    atomicAdd(ws + 18 * NP + 0, s);
  }
}

__global__ void k_final(const float* __restrict__ ws, float* __restrict__ out) {
  float ch = ws[18 * NP + 0];
  float sm = ws[18 * NP + 1];
  float cv = ws[18 * NP + 2];
  out[0] = 0.02f * ch + 0.02f * 0.3f * cv + 0.02f * sm;
}

extern "C" void kernel_launch(void* const* d_in, const int* in_sizes, int n_in,
                              void* d_out, int out_size, void* d_ws, size_t ws_size,
                              hipStream_t stream) {
  (void)in_sizes; (void)n_in; (void)out_size; (void)ws_size;
  const float* pred   = (const float*)d_in[0];
  const float* gt     = (const float*)d_in[1];
  const float* coords = (const float*)d_in[2];
  float* ws  = (float*)d_ws;
  float* out = (float*)d_out;

  k_prep<<<dim3((NP + 255) / 256), dim3(256), 0, stream>>>(pred, gt, coords, ws);
  dim3 g(NP / WPB), b(BLK);
  k_curv_pc2<<<g, b, 0, stream>>>(ws);
  k_pc1<<<g, b, 0, stream>>>(ws);
  k_rev<<<g, b, 0, stream>>>(ws);
  k_cross<<<g, b, 0, stream>>>(ws);
  k_final<<<1, 1, 0, stream>>>(ws, out);
}

// Round 3
// 218.706 us; speedup vs baseline: 2.3003x; 2.3003x over previous
//
#include <hip/hip_runtime.h>
#include <float.h>

#define NP 8192
#define WPB 8            // waves per block
#define BLK (WPB * 64)   // 512 threads
#define QPW 4            // queries per wave
#define QPB (WPB * QPW)  // 32 queries per block
#define NBLK (NP / QPB)  // 256 blocks
#define CHUNK 2048       // candidates staged per LDS chunk (24 KB SoA)
#define CAP2 64          // survivor slots per query (expected ~11)

typedef unsigned long long u64;

// ws layout (floats):
//  0*NP  pc1 x | 1*NP pc1 y | 2*NP pc1 z
//  3*NP  pc2 x,y,z
//  6*NP  warp x,y,z
//  9*NP  flow x,y,z
// 12*NP  c2curv x,y,z
// 15*NP  mcurv x,y,z
// 18*NP  acc[0]=chamfer acc[1]=smooth acc[2]=curv

__device__ __forceinline__ float wavemin_f(float v) {
#pragma unroll
  for (int s = 1; s < 64; s <<= 1) v = fminf(v, __shfl_xor(v, s, 64));
  return v;
}

__device__ __forceinline__ u64 wavemin_u64(u64 k) {
#pragma unroll
  for (int s = 1; s < 64; s <<= 1) {
    u64 o = __shfl_xor(k, s, 64);
    k = (o < k) ? o : k;
  }
  return k;
}

// 512 threads stage CHUNK=2048 floats per array (1 float4 each)
__device__ __forceinline__ void stage2k(const float* __restrict__ gx,
                                        const float* __restrict__ gy,
                                        const float* __restrict__ gz,
                                        float* sx, float* sy, float* sz) {
  const int t = threadIdx.x * 4;
  *(float4*)(sx + t) = *(const float4*)(gx + t);
  *(float4*)(sy + t) = *(const float4*)(gy + t);
  *(float4*)(sz + t) = *(const float4*)(gz + t);
}

#define DIST4(x4, y4, z4, QX, QY, QZ, d0, d1, d2, d3)                     \
  {                                                                       \
    float dx, dy, dz;                                                     \
    dx = x4.x - QX; dy = y4.x - QY; dz = z4.x - QZ;                       \
    d0 = dx * dx + dy * dy + dz * dz;                                     \
    dx = x4.y - QX; dy = y4.y - QY; dz = z4.y - QZ;                       \
    d1 = dx * dx + dy * dy + dz * dz;                                     \
    dx = x4.z - QX; dy = y4.z - QY; dz = z4.z - QZ;                       \
    d2 = dx * dx + dy * dy + dz * dz;                                     \
    dx = x4.w - QX; dy = y4.w - QY; dz = z4.w - QZ;                       \
    d3 = dx * dx + dy * dy + dz * dz;                                     \
  }

__device__ __forceinline__ void append_hit(u64* hq, int* cq, float d, int idx) {
  int p = atomicAdd(cq, 1);
  if (p < CAP2) hq[p] = ((u64)__float_as_uint(d) << 32) | (unsigned)idx;
}

// Two-scan filter for QPW queries per wave.
// scan1: branchless per-lane min per query over the lane's disjoint candidate
//   set. T[q] = K-th smallest of the 64 lane-minima (knockout); the K winner
//   lanes own K distinct candidates <= T so the global K-th smallest <= T.
// scan2: every d <= T[q] appended to hb[q] via LDS atomic counter. Slots are
//   pre-initialized to ~0ull; validity is derived from slot contents.
template<int K>
__device__ __forceinline__ void wave_filter(const float* __restrict__ px,
                                            const float* __restrict__ py,
                                            const float* __restrict__ pz,
                                            const float (&qx)[QPW],
                                            const float (&qy)[QPW],
                                            const float (&qz)[QPW],
                                            float* sx, float* sy, float* sz,
                                            u64 (*hb)[CAP2], int* scnt) {
  const int lane = threadIdx.x & 63;
  float m[QPW];
#pragma unroll
  for (int q = 0; q < QPW; ++q) m[q] = FLT_MAX;

  // ---- scan 1 ----
  for (int c = 0; c < NP; c += CHUNK) {
    __syncthreads();
    stage2k(px + c, py + c, pz + c, sx, sy, sz);
    __syncthreads();
#pragma unroll
    for (int g = 0; g < CHUNK; g += 256) {
      const int o = g + 4 * lane;
      float4 x4 = *(const float4*)(sx + o);
      float4 y4 = *(const float4*)(sy + o);
      float4 z4 = *(const float4*)(sz + o);
#pragma unroll
      for (int q = 0; q < QPW; ++q) {
        float d0, d1, d2, d3;
        DIST4(x4, y4, z4, qx[q], qy[q], qz[q], d0, d1, d2, d3);
        m[q] = fminf(m[q], fminf(fminf(d0, d1), fminf(d2, d3)));
      }
    }
  }

  // ---- thresholds via knockout (4 queries interleaved for ILP) ----
  float T[QPW];
  u64 key[QPW];
#pragma unroll
  for (int q = 0; q < QPW; ++q)
    key[q] = ((u64)__float_as_uint(m[q]) << 32) | (unsigned)lane;
#pragma unroll
  for (int r = 0; r < K; ++r) {
#pragma unroll
    for (int q = 0; q < QPW; ++q) {
      u64 w = wavemin_u64(key[q]);
      if (w == key[q]) key[q] = ~0ull;
      T[q] = __uint_as_float((unsigned)(w >> 32));
    }
  }

  // ---- init survivor buffers (this wave's own region) ----
#pragma unroll
  for (int q = 0; q < QPW; ++q) {
    hb[q][lane] = ~0ull;
    if (lane == 0) scnt[q] = 0;
  }

  // ---- scan 2: collect all d <= T[q] ----
  for (int c = 0; c < NP; c += CHUNK) {
    __syncthreads();
    stage2k(px + c, py + c, pz + c, sx, sy, sz);
    __syncthreads();
#pragma unroll
    for (int g = 0; g < CHUNK; g += 256) {
      const int o = g + 4 * lane;
      const int base = c + o;
      float4 x4 = *(const float4*)(sx + o);
      float4 y4 = *(const float4*)(sy + o);
      float4 z4 = *(const float4*)(sz + o);
#pragma unroll
      for (int q = 0; q < QPW; ++q) {
        float d0, d1, d2, d3;
        DIST4(x4, y4, z4, qx[q], qy[q], qz[q], d0, d1, d2, d3);
        bool h0 = d0 <= T[q], h1 = d1 <= T[q], h2 = d2 <= T[q], h3 = d3 <= T[q];
        if (__ballot(h0 | h1 | h2 | h3) != 0ULL) {
          if (h0) append_hit(hb[q], scnt + q, d0, base + 0);
          if (h1) append_hit(hb[q], scnt + q, d1, base + 1);
          if (h2) append_hit(hb[q], scnt + q, d2, base + 2);
          if (h3) append_hit(hb[q], scnt + q, d3, base + 3);
        }
      }
    }
  }
  __syncthreads();  // survivor writes visible before extraction reads
}

// one extraction round; returns wave-uniform smallest remaining (d,idx) key
// (lexicographic => smallest-index tie-break, matching lax.top_k).
__device__ __forceinline__ u64 extract1(u64& k1) {
  u64 w = wavemin_u64(k1);
  if (w == k1) k1 = ~0ull;
  return w;
}

__global__ void k_prep(const float* __restrict__ pred, const float* __restrict__ gt,
                       const float* __restrict__ coords, float* __restrict__ ws) {
  int i = blockIdx.x * blockDim.x + threadIdx.x;
  if (i < NP) {
    float cx = coords[3 * i], cy = coords[3 * i + 1], cz = coords[3 * i + 2];
    float gx = gt[3 * i],     gy = gt[3 * i + 1],     gz = gt[3 * i + 2];
    float px = pred[3 * i],   py = pred[3 * i + 1],   pz = pred[3 * i + 2];
    ws[0 * NP + i] = cx;      ws[1 * NP + i] = cy;      ws[2 * NP + i] = cz;
    ws[3 * NP + i] = cx + gx; ws[4 * NP + i] = cy + gy; ws[5 * NP + i] = cz + gz;
    ws[6 * NP + i] = cx + px; ws[7 * NP + i] = cy + py; ws[8 * NP + i] = cz + pz;
    ws[9 * NP + i] = px;      ws[10 * NP + i] = py;     ws[11 * NP + i] = pz;
  }
  if (i < 4) ws[18 * NP + i] = 0.f;
}

// pass 1: pc2 x pc2 top-10 -> c2curv
__global__ __launch_bounds__(BLK) void k_curv_pc2(float* __restrict__ ws) {
  __shared__ __align__(16) float sx[CHUNK], sy[CHUNK], sz[CHUNK];
  __shared__ u64 hb[WPB][QPW][CAP2];
  __shared__ int scnt[WPB][QPW];
  const float* px = ws + 3 * NP;
  const float* py = ws + 4 * NP;
  const float* pz = ws + 5 * NP;
  const int wave = threadIdx.x >> 6, lane = threadIdx.x & 63;
  const int i0 = blockIdx.x * QPB + wave * QPW;
  float qx[QPW], qy[QPW], qz[QPW];
#pragma unroll
  for (int q = 0; q < QPW; ++q) {
    qx[q] = px[i0 + q]; qy[q] = py[i0 + q]; qz[q] = pz[i0 + q];
  }
  wave_filter<10>(px, py, pz, qx, qy, qz, sx, sy, sz, hb[wave], scnt[wave]);
#pragma unroll
  for (int q = 0; q < QPW; ++q) {
    u64 k1 = hb[wave][q][lane];
    float ax = 0.f, ay = 0.f, az = 0.f;
#pragma unroll
    for (int r = 0; r < 10; ++r) {
      u64 w = extract1(k1);
      int wj = (w == ~0ull) ? 0 : (int)(w & 0xffffffffULL);
      ax += px[wj]; ay += py[wj]; az += pz[wj];
    }
    if (lane == 0) {
      const float inv9 = 1.f / 9.f;
      const int i = i0 + q;
      ws[12 * NP + i] = (ax - 10.f * qx[q]) * inv9;
      ws[13 * NP + i] = (ay - 10.f * qy[q]) * inv9;
      ws[14 * NP + i] = (az - 10.f * qz[q]) * inv9;
    }
  }
}

// pass 2: pc1 x pc1 top-10 -> mcurv (gather warp) + smooth (top-9, flow norms)
__global__ __launch_bounds__(BLK) void k_pc1(float* __restrict__ ws) {
  __shared__ __align__(16) float sx[CHUNK], sy[CHUNK], sz[CHUNK];
  __shared__ u64 hb[WPB][QPW][CAP2];
  __shared__ int scnt[WPB][QPW];
  __shared__ float red[WPB];
  const float* px = ws;
  const float* py = ws + NP;
  const float* pz = ws + 2 * NP;
  const float* wx = ws + 6 * NP;
  const float* wy = ws + 7 * NP;
  const float* wz = ws + 8 * NP;
  const float* fx = ws + 9 * NP;
  const float* fy = ws + 10 * NP;
  const float* fz = ws + 11 * NP;
  const int wave = threadIdx.x >> 6, lane = threadIdx.x & 63;
  const int i0 = blockIdx.x * QPB + wave * QPW;
  float qx[QPW], qy[QPW], qz[QPW];
#pragma unroll
  for (int q = 0; q < QPW; ++q) {
    qx[q] = px[i0 + q]; qy[q] = py[i0 + q]; qz[q] = pz[i0 + q];
  }
  wave_filter<10>(px, py, pz, qx, qy, qz, sx, sy, sz, hb[wave], scnt[wave]);
  float smw = 0.f;
#pragma unroll
  for (int q = 0; q < QPW; ++q) {
    const int i = i0 + q;
    const float fix = fx[i], fiy = fy[i], fiz = fz[i];
    const float wix = wx[i], wiy = wy[i], wiz = wz[i];
    u64 k1 = hb[wave][q][lane];
    float ax = 0.f, ay = 0.f, az = 0.f, sm = 0.f;
#pragma unroll
    for (int r = 0; r < 10; ++r) {
      u64 w = extract1(k1);
      int wj = (w == ~0ull) ? 0 : (int)(w & 0xffffffffULL);
      ax += wx[wj]; ay += wy[wj]; az += wz[wj];
      if (r < 9) {
        float gx_ = fx[wj] - fix, gy_ = fy[wj] - fiy, gz_ = fz[wj] - fiz;
        sm += sqrtf(gx_ * gx_ + gy_ * gy_ + gz_ * gz_);
      }
    }
    smw += sm * 0.125f;
    if (lane == 0) {
      const float inv9 = 1.f / 9.f;
      ws[15 * NP + i] = (ax - 10.f * wix) * inv9;
      ws[16 * NP + i] = (ay - 10.f * wiy) * inv9;
      ws[17 * NP + i] = (az - 10.f * wiz) * inv9;
    }
  }
  if (lane == 0) red[wave] = smw;
  __syncthreads();
  if (threadIdx.x == 0) {
    float s = 0.f;
#pragma unroll
    for (int t = 0; t < WPB; ++t) s += red[t];
    atomicAdd(ws + 18 * NP + 1, s);
  }
}

// pass 3: warp x pc2 top-5 -> chamfer dist1 + interpolated-curvature loss
__global__ __launch_bounds__(BLK) void k_cross(float* __restrict__ ws) {
  __shared__ __align__(16) float sx[CHUNK], sy[CHUNK], sz[CHUNK];
  __shared__ u64 hb[WPB][QPW][CAP2];
  __shared__ int scnt[WPB][QPW];
  __shared__ float redc[WPB], redv[WPB];
  const float* px = ws + 3 * NP;   // pc2 candidates
  const float* py = ws + 4 * NP;
  const float* pz = ws + 5 * NP;
  const float* wx = ws + 6 * NP;   // warp queries
  const float* wy = ws + 7 * NP;
  const float* wz = ws + 8 * NP;
  const float* cx = ws + 12 * NP;  // c2curv
  const float* cy = ws + 13 * NP;
  const float* cz = ws + 14 * NP;
  const float* mx = ws + 15 * NP;  // mcurv
  const float* my = ws + 16 * NP;
  const float* mz = ws + 17 * NP;
  const int wave = threadIdx.x >> 6, lane = threadIdx.x & 63;
  const int i0 = blockIdx.x * QPB + wave * QPW;
  float qx[QPW], qy[QPW], qz[QPW];
#pragma unroll
  for (int q = 0; q < QPW; ++q) {
    qx[q] = wx[i0 + q]; qy[q] = wy[i0 + q]; qz[q] = wz[i0 + q];
  }
  wave_filter<5>(px, py, pz, qx, qy, qz, sx, sy, sz, hb[wave], scnt[wave]);
  float csum = 0.f, vsum = 0.f;
#pragma unroll
  for (int q = 0; q < QPW; ++q) {
    const int i = i0 + q;
    u64 k1 = hb[wave][q][lane];
    float wsum = 0.f, ix = 0.f, iy = 0.f, iz = 0.f, d1 = 0.f;
#pragma unroll
    for (int r = 0; r < 5; ++r) {
      u64 w = extract1(k1);
      bool valid = (w != ~0ull);
      float wd = valid ? __uint_as_float((unsigned)(w >> 32)) : FLT_MAX;
      int wj = valid ? (int)(w & 0xffffffffULL) : 0;
      if (r == 0) d1 = wd;
      float wt = 1.f / (wd + 1e-8f);
      wsum += wt;
      ix += wt * cx[wj]; iy += wt * cy[wj]; iz += wt * cz[wj];
    }
    float inv = 1.f / wsum;
    float ex = ix * inv - mx[i];
    float ey = iy * inv - my[i];
    float ez = iz * inv - mz[i];
    csum += d1;
    vsum += ex * ex + ey * ey + ez * ez;
  }
  if (lane == 0) { redc[wave] = csum; redv[wave] = vsum; }
  __syncthreads();
  if (threadIdx.x == 0) {
    float sc = 0.f, sv = 0.f;
#pragma unroll
    for (int t = 0; t < WPB; ++t) { sc += redc[t]; sv += redv[t]; }
    atomicAdd(ws + 18 * NP + 0, sc);
    atomicAdd(ws + 18 * NP + 2, sv);
  }
}

// pass 4: pc2 x warp top-1 -> chamfer dist2 (branchless single scan)
__global__ __launch_bounds__(BLK) void k_rev(float* __restrict__ ws) {
  __shared__ __align__(16) float sx[CHUNK], sy[CHUNK], sz[CHUNK];
  __shared__ float red[WPB];
  const float* px = ws + 6 * NP;   // warp candidates
  const float* py = ws + 7 * NP;
  const float* pz = ws + 8 * NP;
  const float* gx = ws + 3 * NP;   // pc2 queries
  const float* gy = ws + 4 * NP;
  const float* gz = ws + 5 * NP;
  const int wave = threadIdx.x >> 6, lane = threadIdx.x & 63;
  const int i0 = blockIdx.x * QPB + wave * QPW;
  float qx[QPW], qy[QPW], qz[QPW], m[QPW];
#pragma unroll
  for (int q = 0; q < QPW; ++q) {
    qx[q] = gx[i0 + q]; qy[q] = gy[i0 + q]; qz[q] = gz[i0 + q];
    m[q] = FLT_MAX;
  }
  for (int c = 0; c < NP; c += CHUNK) {
    __syncthreads();
    stage2k(px + c, py + c, pz + c, sx, sy, sz);
    __syncthreads();
#pragma unroll
    for (int g = 0; g < CHUNK; g += 256) {
      const int o = g + 4 * lane;
      float4 x4 = *(const float4*)(sx + o);
      float4 y4 = *(const float4*)(sy + o);
      float4 z4 = *(const float4*)(sz + o);
#pragma unroll
      for (int q = 0; q < QPW; ++q) {
        float d0, d1, d2, d3;
        DIST4(x4, y4, z4, qx[q], qy[q], qz[q], d0, d1, d2, d3);
        m[q] = fminf(m[q], fminf(fminf(d0, d1), fminf(d2, d3)));
      }
    }
  }
  float s = 0.f;
#pragma unroll
  for (int q = 0; q < QPW; ++q) s += wavemin_f(m[q]);
  if (lane == 0) red[wave] = s;
  __syncthreads();
  if (threadIdx.x == 0) {
    float t0 = 0.f;
#pragma unroll
    for (int t = 0; t < WPB; ++t) t0 += red[t];
    atomicAdd(ws + 18 * NP + 0, t0);
  }
}

__global__ void k_final(const float* __restrict__ ws, float* __restrict__ out) {
  float ch = ws[18 * NP + 0];
  float sm = ws[18 * NP + 1];
  float cv = ws[18 * NP + 2];
  out[0] = 0.02f * ch + 0.02f * 0.3f * cv + 0.02f * sm;
}

extern "C" void kernel_launch(void* const* d_in, const int* in_sizes, int n_in,
                              void* d_out, int out_size, void* d_ws, size_t ws_size,
                              hipStream_t stream) {
  (void)in_sizes; (void)n_in; (void)out_size; (void)ws_size;
  const float* pred   = (const float*)d_in[0];
  const float* gt     = (const float*)d_in[1];
  const float* coords = (const float*)d_in[2];
  float* ws  = (float*)d_ws;
  float* out = (float*)d_out;

  k_prep<<<dim3((NP + 255) / 256), dim3(256), 0, stream>>>(pred, gt, coords, ws);
  dim3 g(NBLK), b(BLK);
  k_curv_pc2<<<g, b, 0, stream>>>(ws);
  k_pc1<<<g, b, 0, stream>>>(ws);
  k_rev<<<g, b, 0, stream>>>(ws);
  k_cross<<<g, b, 0, stream>>>(ws);
  k_final<<<1, 1, 0, stream>>>(ws, out);
}

// Round 4
// 163.936 us; speedup vs baseline: 3.0688x; 1.3341x over previous
//
#include <hip/hip_runtime.h>
#include <float.h>

#define NP 8192
#define WPB 4            // waves per block
#define BLK (WPB * 64)   // 256 threads
#define QPW 4            // queries per wave
#define QPB (WPB * QPW)  // 16 queries per block
#define NBLK (NP / QPB)  // 512 blocks -> 2 blocks/CU
#define CHUNK 2048       // candidates per LDS chunk (32 KB xyzw SoA)
#define CAP2 64          // survivor slots per query (expected ~11)

typedef unsigned long long u64;

// ws layout (floats):
//  0..3  *NP  pc1  x,y,z,w(|p|^2)
//  4..7  *NP  pc2  x,y,z,w
//  8..11 *NP  warp x,y,z,w
// 12..14 *NP  flow x,y,z
// 15..17 *NP  c2curv x,y,z
// 18..20 *NP  mcurv  x,y,z
// 21*NP      acc[0]=chamfer acc[1]=smooth acc[2]=curv

__device__ __forceinline__ float wavemin_f(float v) {
#pragma unroll
  for (int s = 1; s < 64; s <<= 1) v = fminf(v, __shfl_xor(v, s, 64));
  return v;
}

// score = |p|^2 - 2 p.q  (nq* = -2*q*); d = score + |q|^2. Identical FMA
// sequence used in scan1 and scan2 so thresholds compare bitwise-consistent.
__device__ __forceinline__ float score1(float x, float y, float z, float w,
                                        float nx, float ny, float nz) {
  return fmaf(x, nx, fmaf(y, ny, fmaf(z, nz, w)));
}

// 256 threads stage CHUNK=2048 floats per array
__device__ __forceinline__ void stage4(const float* __restrict__ gx,
                                       const float* __restrict__ gy,
                                       const float* __restrict__ gz,
                                       const float* __restrict__ gw,
                                       float* sx, float* sy, float* sz, float* sw) {
  const int t = threadIdx.x * 4;
#pragma unroll
  for (int h = 0; h < CHUNK; h += 1024) {
    *(float4*)(sx + t + h) = *(const float4*)(gx + t + h);
    *(float4*)(sy + t + h) = *(const float4*)(gy + t + h);
    *(float4*)(sz + t + h) = *(const float4*)(gz + t + h);
    *(float4*)(sw + t + h) = *(const float4*)(gw + t + h);
  }
}

// smallest remaining (s,j) across the wave; arbitrary-but-consistent pick on
// exact float ties (prob ~0 on random data; absmax tolerance covers it).
__device__ __forceinline__ void extract1f(float& s, int& j, int lane,
                                          float& od, int& oj) {
  float w = wavemin_f(s);
  u64 msk = __ballot(s == w);
  int src = (int)__ffsll(msk) - 1;
  oj = __shfl(j, src, 64);
  if (lane == src) s = FLT_MAX;
  od = w;
}

// Two-scan filter for QPW queries per wave.
// scan1: branchless per-lane min score. T[q] = K-th smallest of the 64
//   lane-minima (value knockout); the K knocked-out lanes own K distinct
//   candidates <= T so the global K-th smallest <= T.
// scan2: every score <= T[q] appended via LDS atomic counter; slots
//   pre-initialized to FLT_MAX so validity is data-derived.
template<int K>
__device__ __forceinline__ void wave_filter(const float* __restrict__ px,
                                            const float* __restrict__ py,
                                            const float* __restrict__ pz,
                                            const float* __restrict__ pw,
                                            const float (&nqx)[QPW],
                                            const float (&nqy)[QPW],
                                            const float (&nqz)[QPW],
                                            float* sx, float* sy, float* sz, float* sw,
                                            float (*hs)[CAP2], int (*hj)[CAP2],
                                            int* scnt, float (&T)[QPW]) {
  const int lane = threadIdx.x & 63;
  float m[QPW];
#pragma unroll
  for (int q = 0; q < QPW; ++q) m[q] = FLT_MAX;

  // ---- scan 1 ----
  for (int c = 0; c < NP; c += CHUNK) {
    __syncthreads();
    stage4(px + c, py + c, pz + c, pw + c, sx, sy, sz, sw);
    __syncthreads();
#pragma unroll 4
    for (int g = 0; g < CHUNK; g += 256) {
      const int o = g + 4 * lane;
      float4 X = *(const float4*)(sx + o);
      float4 Y = *(const float4*)(sy + o);
      float4 Z = *(const float4*)(sz + o);
      float4 W = *(const float4*)(sw + o);
#pragma unroll
      for (int q = 0; q < QPW; ++q) {
        float s0 = score1(X.x, Y.x, Z.x, W.x, nqx[q], nqy[q], nqz[q]);
        float s1 = score1(X.y, Y.y, Z.y, W.y, nqx[q], nqy[q], nqz[q]);
        float s2 = score1(X.z, Y.z, Z.z, W.z, nqx[q], nqy[q], nqz[q]);
        float s3 = score1(X.w, Y.w, Z.w, W.w, nqx[q], nqy[q], nqz[q]);
        m[q] = fminf(m[q], fminf(fminf(s0, s1), fminf(s2, s3)));
      }
    }
  }

  // ---- threshold: K-th smallest lane-min via value knockout ----
#pragma unroll
  for (int q = 0; q < QPW; ++q) {
    float mm = m[q], t = 0.f;
#pragma unroll
    for (int r = 0; r < K; ++r) {
      float w = wavemin_f(mm);
      u64 msk = __ballot(mm == w);
      if (lane == (int)__ffsll(msk) - 1) mm = FLT_MAX;
      t = w;
    }
    T[q] = t;
  }

  // ---- init survivor buffers ----
#pragma unroll
  for (int q = 0; q < QPW; ++q) {
    hs[q][lane] = FLT_MAX;
    hj[q][lane] = 0;
    if (lane == 0) scnt[q] = 0;
  }

  // ---- scan 2: collect all score <= T[q] ----
  for (int c = 0; c < NP; c += CHUNK) {
    __syncthreads();
    stage4(px + c, py + c, pz + c, pw + c, sx, sy, sz, sw);
    __syncthreads();
#pragma unroll 4
    for (int g = 0; g < CHUNK; g += 256) {
      const int o = g + 4 * lane;
      const int base = c + o;
      float4 X = *(const float4*)(sx + o);
      float4 Y = *(const float4*)(sy + o);
      float4 Z = *(const float4*)(sz + o);
      float4 W = *(const float4*)(sw + o);
#pragma unroll
      for (int q = 0; q < QPW; ++q) {
        float s0 = score1(X.x, Y.x, Z.x, W.x, nqx[q], nqy[q], nqz[q]);
        float s1 = score1(X.y, Y.y, Z.y, W.y, nqx[q], nqy[q], nqz[q]);
        float s2 = score1(X.z, Y.z, Z.z, W.z, nqx[q], nqy[q], nqz[q]);
        float s3 = score1(X.w, Y.w, Z.w, W.w, nqx[q], nqy[q], nqz[q]);
        float gm = fminf(fminf(s0, s1), fminf(s2, s3));
        if (__ballot(gm <= T[q]) != 0ULL) {
          if (s0 <= T[q]) { int p = atomicAdd(scnt + q, 1); if (p < CAP2) { hs[q][p] = s0; hj[q][p] = base + 0; } }
          if (s1 <= T[q]) { int p = atomicAdd(scnt + q, 1); if (p < CAP2) { hs[q][p] = s1; hj[q][p] = base + 1; } }
          if (s2 <= T[q]) { int p = atomicAdd(scnt + q, 1); if (p < CAP2) { hs[q][p] = s2; hj[q][p] = base + 2; } }
          if (s3 <= T[q]) { int p = atomicAdd(scnt + q, 1); if (p < CAP2) { hs[q][p] = s3; hj[q][p] = base + 3; } }
        }
      }
    }
  }
  __syncthreads();  // survivor writes visible before extraction
}

__global__ void k_prep(const float* __restrict__ pred, const float* __restrict__ gt,
                       const float* __restrict__ coords, float* __restrict__ ws) {
  int i = blockIdx.x * blockDim.x + threadIdx.x;
  if (i < NP) {
    float cx = coords[3 * i], cy = coords[3 * i + 1], cz = coords[3 * i + 2];
    float gx = gt[3 * i],     gy = gt[3 * i + 1],     gz = gt[3 * i + 2];
    float px = pred[3 * i],   py = pred[3 * i + 1],   pz = pred[3 * i + 2];
    float ax = cx + gx, ay = cy + gy, az = cz + gz;   // pc2
    float bx = cx + px, by = cy + py, bz = cz + pz;   // warp
    ws[0 * NP + i] = cx; ws[1 * NP + i] = cy; ws[2 * NP + i] = cz;
    ws[3 * NP + i] = cx * cx + cy * cy + cz * cz;
    ws[4 * NP + i] = ax; ws[5 * NP + i] = ay; ws[6 * NP + i] = az;
    ws[7 * NP + i] = ax * ax + ay * ay + az * az;
    ws[8 * NP + i] = bx; ws[9 * NP + i] = by; ws[10 * NP + i] = bz;
    ws[11 * NP + i] = bx * bx + by * by + bz * bz;
    ws[12 * NP + i] = px; ws[13 * NP + i] = py; ws[14 * NP + i] = pz;
  }
  if (i < 4) ws[21 * NP + i] = 0.f;
}

// pass 1: pc2 x pc2 top-10 -> c2curv
__global__ __launch_bounds__(BLK) void k_curv_pc2(float* __restrict__ ws) {
  __shared__ __align__(16) float sx[CHUNK], sy[CHUNK], sz[CHUNK], sw[CHUNK];
  __shared__ float hs[WPB][QPW][CAP2];
  __shared__ int hj[WPB][QPW][CAP2];
  __shared__ int scnt[WPB][QPW];
  const float* px = ws + 4 * NP; const float* py = ws + 5 * NP;
  const float* pz = ws + 6 * NP; const float* pw = ws + 7 * NP;
  const int wave = threadIdx.x >> 6, lane = threadIdx.x & 63;
  const int i0 = blockIdx.x * QPB + wave * QPW;
  float qx[QPW], qy[QPW], qz[QPW], nqx[QPW], nqy[QPW], nqz[QPW], T[QPW];
#pragma unroll
  for (int q = 0; q < QPW; ++q) {
    qx[q] = px[i0 + q]; qy[q] = py[i0 + q]; qz[q] = pz[i0 + q];
    nqx[q] = -2.f * qx[q]; nqy[q] = -2.f * qy[q]; nqz[q] = -2.f * qz[q];
  }
  wave_filter<10>(px, py, pz, pw, nqx, nqy, nqz, sx, sy, sz, sw,
                  hs[wave], hj[wave], scnt[wave], T);
#pragma unroll
  for (int q = 0; q < QPW; ++q) {
    float s = hs[wave][q][lane]; int j = hj[wave][q][lane];
    float ax = 0.f, ay = 0.f, az = 0.f;
#pragma unroll
    for (int r = 0; r < 10; ++r) {
      float od; int oj;
      extract1f(s, j, lane, od, oj);
      ax += px[oj]; ay += py[oj]; az += pz[oj];
    }
    if (lane == 0) {
      const float inv9 = 1.f / 9.f;
      const int i = i0 + q;
      ws[15 * NP + i] = (ax - 10.f * qx[q]) * inv9;
      ws[16 * NP + i] = (ay - 10.f * qy[q]) * inv9;
      ws[17 * NP + i] = (az - 10.f * qz[q]) * inv9;
    }
  }
}

// pass 2: pc1 x pc1 top-10 -> mcurv (gather warp) + smooth (top-9, flow norms)
__global__ __launch_bounds__(BLK) void k_pc1(float* __restrict__ ws) {
  __shared__ __align__(16) float sx[CHUNK], sy[CHUNK], sz[CHUNK], sw[CHUNK];
  __shared__ float hs[WPB][QPW][CAP2];
  __shared__ int hj[WPB][QPW][CAP2];
  __shared__ int scnt[WPB][QPW];
  __shared__ float red[WPB];
  const float* px = ws + 0 * NP; const float* py = ws + 1 * NP;
  const float* pz = ws + 2 * NP; const float* pw = ws + 3 * NP;
  const float* wx = ws + 8 * NP; const float* wy = ws + 9 * NP;
  const float* wz = ws + 10 * NP;
  const float* fx = ws + 12 * NP; const float* fy = ws + 13 * NP;
  const float* fz = ws + 14 * NP;
  const int wave = threadIdx.x >> 6, lane = threadIdx.x & 63;
  const int i0 = blockIdx.x * QPB + wave * QPW;
  float nqx[QPW], nqy[QPW], nqz[QPW], T[QPW];
#pragma unroll
  for (int q = 0; q < QPW; ++q) {
    nqx[q] = -2.f * px[i0 + q]; nqy[q] = -2.f * py[i0 + q]; nqz[q] = -2.f * pz[i0 + q];
  }
  wave_filter<10>(px, py, pz, pw, nqx, nqy, nqz, sx, sy, sz, sw,
                  hs[wave], hj[wave], scnt[wave], T);
  float smw = 0.f;
#pragma unroll
  for (int q = 0; q < QPW; ++q) {
    const int i = i0 + q;
    const float fix = fx[i], fiy = fy[i], fiz = fz[i];
    const float wix = wx[i], wiy = wy[i], wiz = wz[i];
    float s = hs[wave][q][lane]; int j = hj[wave][q][lane];
    float ax = 0.f, ay = 0.f, az = 0.f, sm = 0.f;
#pragma unroll
    for (int r = 0; r < 10; ++r) {
      float od; int oj;
      extract1f(s, j, lane, od, oj);
      ax += wx[oj]; ay += wy[oj]; az += wz[oj];
      if (r < 9) {
        float gx_ = fx[oj] - fix, gy_ = fy[oj] - fiy, gz_ = fz[oj] - fiz;
        sm += sqrtf(gx_ * gx_ + gy_ * gy_ + gz_ * gz_);
      }
    }
    smw += sm * 0.125f;
    if (lane == 0) {
      const float inv9 = 1.f / 9.f;
      ws[18 * NP + i] = (ax - 10.f * wix) * inv9;
      ws[19 * NP + i] = (ay - 10.f * wiy) * inv9;
      ws[20 * NP + i] = (az - 10.f * wiz) * inv9;
    }
  }
  if (lane == 0) red[wave] = smw;
  __syncthreads();
  if (threadIdx.x == 0) {
    float s = 0.f;
#pragma unroll
    for (int t = 0; t < WPB; ++t) s += red[t];
    atomicAdd(ws + 21 * NP + 1, s);
  }
}

// pass 3: warp x pc2 top-5 -> chamfer dist1 + interpolated-curvature loss
__global__ __launch_bounds__(BLK) void k_cross(float* __restrict__ ws) {
  __shared__ __align__(16) float sx[CHUNK], sy[CHUNK], sz[CHUNK], sw[CHUNK];
  __shared__ float hs[WPB][QPW][CAP2];
  __shared__ int hj[WPB][QPW][CAP2];
  __shared__ int scnt[WPB][QPW];
  __shared__ float redc[WPB], redv[WPB];
  const float* px = ws + 4 * NP; const float* py = ws + 5 * NP;
  const float* pz = ws + 6 * NP; const float* pw = ws + 7 * NP;   // pc2 cands
  const float* wx = ws + 8 * NP; const float* wy = ws + 9 * NP;
  const float* wz = ws + 10 * NP; const float* ww = ws + 11 * NP; // warp queries
  const float* cx = ws + 15 * NP; const float* cy = ws + 16 * NP;
  const float* cz = ws + 17 * NP;                                 // c2curv
  const float* mx = ws + 18 * NP; const float* my = ws + 19 * NP;
  const float* mz = ws + 20 * NP;                                 // mcurv
  const int wave = threadIdx.x >> 6, lane = threadIdx.x & 63;
  const int i0 = blockIdx.x * QPB + wave * QPW;
  float nqx[QPW], nqy[QPW], nqz[QPW], qw[QPW], T[QPW];
#pragma unroll
  for (int q = 0; q < QPW; ++q) {
    nqx[q] = -2.f * wx[i0 + q]; nqy[q] = -2.f * wy[i0 + q]; nqz[q] = -2.f * wz[i0 + q];
    qw[q] = ww[i0 + q];
  }
  wave_filter<5>(px, py, pz, pw, nqx, nqy, nqz, sx, sy, sz, sw,
                 hs[wave], hj[wave], scnt[wave], T);
  float csum = 0.f, vsum = 0.f;
#pragma unroll
  for (int q = 0; q < QPW; ++q) {
    const int i = i0 + q;
    float s = hs[wave][q][lane]; int j = hj[wave][q][lane];
    float wsum = 0.f, ix = 0.f, iy = 0.f, iz = 0.f, d1 = 0.f;
#pragma unroll
    for (int r = 0; r < 5; ++r) {
      float od; int oj;
      extract1f(s, j, lane, od, oj);
      float d = od + qw[q];           // true squared distance (ref's expanded form)
      if (r == 0) d1 = d;
      float wt = 1.f / (d + 1e-8f);
      wsum += wt;
      ix += wt * cx[oj]; iy += wt * cy[oj]; iz += wt * cz[oj];
    }
    float inv = 1.f / wsum;
    float ex = ix * inv - mx[i];
    float ey = iy * inv - my[i];
    float ez = iz * inv - mz[i];
    csum += d1;
    vsum += ex * ex + ey * ey + ez * ez;
  }
  if (lane == 0) { redc[wave] = csum; redv[wave] = vsum; }
  __syncthreads();
  if (threadIdx.x == 0) {
    float sc = 0.f, sv = 0.f;
#pragma unroll
    for (int t = 0; t < WPB; ++t) { sc += redc[t]; sv += redv[t]; }
    atomicAdd(ws + 21 * NP + 0, sc);
    atomicAdd(ws + 21 * NP + 2, sv);
  }
}

// pass 4: pc2 x warp top-1 -> chamfer dist2 (branchless single scan)
__global__ __launch_bounds__(BLK) void k_rev(float* __restrict__ ws) {
  __shared__ __align__(16) float sx[CHUNK], sy[CHUNK], sz[CHUNK], sw[CHUNK];
  __shared__ float red[WPB];
  const float* px = ws + 8 * NP; const float* py = ws + 9 * NP;
  const float* pz = ws + 10 * NP; const float* pw = ws + 11 * NP; // warp cands
  const float* gx = ws + 4 * NP; const float* gy = ws + 5 * NP;
  const float* gz = ws + 6 * NP; const float* gw = ws + 7 * NP;   // pc2 queries
  const int wave = threadIdx.x >> 6, lane = threadIdx.x & 63;
  const int i0 = blockIdx.x * QPB + wave * QPW;
  float nqx[QPW], nqy[QPW], nqz[QPW], qw[QPW], m[QPW];
#pragma unroll
  for (int q = 0; q < QPW; ++q) {
    nqx[q] = -2.f * gx[i0 + q]; nqy[q] = -2.f * gy[i0 + q]; nqz[q] = -2.f * gz[i0 + q];
    qw[q] = gw[i0 + q];
    m[q] = FLT_MAX;
  }
  for (int c = 0; c < NP; c += CHUNK) {
    __syncthreads();
    stage4(px + c, py + c, pz + c, pw + c, sx, sy, sz, sw);
    __syncthreads();
#pragma unroll 4
    for (int g = 0; g < CHUNK; g += 256) {
      const int o = g + 4 * lane;
      float4 X = *(const float4*)(sx + o);
      float4 Y = *(const float4*)(sy + o);
      float4 Z = *(const float4*)(sz + o);
      float4 W = *(const float4*)(sw + o);
#pragma unroll
      for (int q = 0; q < QPW; ++q) {
        float s0 = score1(X.x, Y.x, Z.x, W.x, nqx[q], nqy[q], nqz[q]);
        float s1 = score1(X.y, Y.y, Z.y, W.y, nqx[q], nqy[q], nqz[q]);
        float s2 = score1(X.z, Y.z, Z.z, W.z, nqx[q], nqy[q], nqz[q]);
        float s3 = score1(X.w, Y.w, Z.w, W.w, nqx[q], nqy[q], nqz[q]);
        m[q] = fminf(m[q], fminf(fminf(s0, s1), fminf(s2, s3)));
      }
    }
  }
  float s = 0.f;
#pragma unroll
  for (int q = 0; q < QPW; ++q) s += wavemin_f(m[q]) + qw[q];
  if (lane == 0) red[wave] = s;
  __syncthreads();
  if (threadIdx.x == 0) {
    float t0 = 0.f;
#pragma unroll
    for (int t = 0; t < WPB; ++t) t0 += red[t];
    atomicAdd(ws + 21 * NP + 0, t0);
  }
}

__global__ void k_final(const float* __restrict__ ws, float* __restrict__ out) {
  float ch = ws[21 * NP + 0];
  float sm = ws[21 * NP + 1];
  float cv = ws[21 * NP + 2];
  out[0] = 0.02f * ch + 0.02f * 0.3f * cv + 0.02f * sm;
}

extern "C" void kernel_launch(void* const* d_in, const int* in_sizes, int n_in,
                              void* d_out, int out_size, void* d_ws, size_t ws_size,
                              hipStream_t stream) {
  (void)in_sizes; (void)n_in; (void)out_size; (void)ws_size;
  const float* pred   = (const float*)d_in[0];
  const float* gt     = (const float*)d_in[1];
  const float* coords = (const float*)d_in[2];
  float* ws  = (float*)d_ws;
  float* out = (float*)d_out;

  k_prep<<<dim3((NP + BLK - 1) / BLK), dim3(BLK), 0, stream>>>(pred, gt, coords, ws);
  dim3 g(NBLK), b(BLK);
  k_curv_pc2<<<g, b, 0, stream>>>(ws);
  k_pc1<<<g, b, 0, stream>>>(ws);
  k_rev<<<g, b, 0, stream>>>(ws);
  k_cross<<<g, b, 0, stream>>>(ws);
  k_final<<<1, 1, 0, stream>>>(ws, out);
}